// Round 10
// baseline (409.851 us; speedup 1.0000x reference)
//
#include <hip/hip_runtime.h>

#define BB 4
#define TT 32
#define DD 256
#define NN 1024

typedef unsigned long long u64;
typedef unsigned u32;

// ws layout in u64 units. Total 327680 u64 + 40 KB tags = 2.66 MB (< 3.28 MB proven).
// All shared data moves as packed f32-pairs via UC relaxed atomics (always fresh; no
// fences). Tags (written AFTER __syncthreads' vmcnt(0) drain of the UC data stores)
// prove completion. Poison 0xAA never matches any tag; all slots write-once per launch.
#define XN64 0          // xn pairs [128][512]
#define TN64 65536      // tn pairs [128][512]  (tn[bt] = tgt_neurons[bt+1]; t=31 unused)
#define P64O 131072     // p pairs  [128][2][512]
#define R64O 262144     // r pairs  [128][512]
#define TAGO 327680     // u32 tag region: xtag[128*16], ttag[128*16], ptag[128*2*16], rtag[128*16]

__device__ __forceinline__ u64 uld(const u64* p){ return __hip_atomic_load(p, __ATOMIC_RELAXED, __HIP_MEMORY_SCOPE_AGENT); }
__device__ __forceinline__ void ust(u64* p, u64 v){ __hip_atomic_store(p, v, __ATOMIC_RELAXED, __HIP_MEMORY_SCOPE_AGENT); }
__device__ __forceinline__ u32 uld32(const u32* p){ return __hip_atomic_load(p, __ATOMIC_RELAXED, __HIP_MEMORY_SCOPE_AGENT); }
__device__ __forceinline__ void ust32(u32* p, u32 v){ __hip_atomic_store(p, v, __ATOMIC_RELAXED, __HIP_MEMORY_SCOPE_AGENT); }
__device__ __forceinline__ u64 pk2(float a, float b){ return (u64)__float_as_uint(a) | ((u64)__float_as_uint(b) << 32); }
__device__ __forceinline__ float flo(u64 u){ return __uint_as_float((u32)u); }
__device__ __forceinline__ float fhi(u64 u){ return __uint_as_float((u32)(u >> 32)); }

__global__ __launch_bounds__(512, 2) void fused_kernel(
    const float* __restrict__ x_seq, const float* __restrict__ targets,
    const float* __restrict__ E, const float* __restrict__ Dy,
    float* __restrict__ out, float* __restrict__ wsf)
{
    __shared__ float sh[6144];   // [0..1087] staging | [2048..4095] myp1 | [4096..6143] myp2
    u64* wsu  = (u64*)wsf;
    u64* xn64 = wsu + XN64;
    u64* tn64 = wsu + TN64;
    u64* p64  = wsu + P64O;
    u64* r64  = wsu + R64O;
    u32* xtag = (u32*)(wsu + TAGO);   // [bt*16]
    u32* ttag = xtag + 2048;          // [bt*16]
    u32* ptag = ttag + 2048;          // [(bt*2+ph)*16 + wg]
    u32* rtag = ptag + 4096;          // [bt*16 + wg]

    const int blk  = blockIdx.x;
    const int tid  = threadIdx.x;
    const int lane = tid & 63;
    const int w    = tid >> 6;

    if (blk < 64) {
        // ================= precompute role: xn/tn = relu(LN(row @ E)) =================
        const int bt0 = blk * 2, bt1 = bt0 + 1;
        const int half = tid >> 8;          // 0: x_seq rows, 1: targets rows
        const int th   = tid & 255;
        const int wq   = w & 3;
        const float* srcx = half ? targets : x_seq;
        sh[(half*2+0)*256 + th] = srcx[(size_t)bt0 * DD + th];
        sh[(half*2+1)*256 + th] = srcx[(size_t)bt1 * DD + th];
        __syncthreads();
        const float4* E4 = (const float4*)E;
        float4 a0 = make_float4(0.f,0.f,0.f,0.f), a1 = make_float4(0.f,0.f,0.f,0.f);
#pragma unroll 4
        for (int k = 0; k < DD; ++k) {
            float4 e = E4[(size_t)k * (NN/4) + th];
            float x0 = sh[(half*2+0)*256 + k];
            float x1 = sh[(half*2+1)*256 + k];
            a0.x += x0*e.x; a0.y += x0*e.y; a0.z += x0*e.z; a0.w += x0*e.w;
            a1.x += x1*e.x; a1.y += x1*e.y; a1.z += x1*e.z; a1.w += x1*e.w;
        }
        float s[2], q[2];
        s[0] = a0.x+a0.y+a0.z+a0.w; q[0] = a0.x*a0.x+a0.y*a0.y+a0.z*a0.z+a0.w*a0.w;
        s[1] = a1.x+a1.y+a1.z+a1.w; q[1] = a1.x*a1.x+a1.y*a1.y+a1.z*a1.z+a1.w*a1.w;
#pragma unroll
        for (int d = 1; d < 64; d <<= 1) {
            s[0] += __shfl_xor(s[0], d, 64); q[0] += __shfl_xor(q[0], d, 64);
            s[1] += __shfl_xor(s[1], d, 64); q[1] += __shfl_xor(q[1], d, 64);
        }
        if (lane == 0) {
            sh[5120 + (half*2+0)*4 + wq] = s[0]; sh[5152 + (half*2+0)*4 + wq] = q[0];
            sh[5120 + (half*2+1)*4 + wq] = s[1]; sh[5152 + (half*2+1)*4 + wq] = q[1];
        }
        __syncthreads();
#pragma unroll
        for (int r = 0; r < 2; ++r) {
            float S = 0.f, Q = 0.f;
#pragma unroll
            for (int j = 0; j < 4; ++j) {
                S += sh[5120 + (half*2+r)*4 + j];
                Q += sh[5152 + (half*2+r)*4 + j];
            }
            const float mu  = S * (1.0f / NN);
            const float var = Q * (1.0f / NN) - mu * mu;
            const float inv = rsqrtf(var + 1e-5f);
            float4 a = r ? a1 : a0;
            float o0 = fmaxf(0.f, (a.x - mu) * inv);
            float o1 = fmaxf(0.f, (a.y - mu) * inv);
            float o2 = fmaxf(0.f, (a.z - mu) * inv);
            float o3 = fmaxf(0.f, (a.w - mu) * inv);
            const int bt = r ? bt1 : bt0;
            if (half == 0) {
                u64* d = xn64 + (size_t)bt * 512 + th * 2;
                ust(d, pk2(o0, o1)); ust(d + 1, pk2(o2, o3));
            } else if ((bt & 31) > 0) {
                u64* d = tn64 + (size_t)(bt - 1) * 512 + th * 2;
                ust(d, pk2(o0, o1)); ust(d + 1, pk2(o2, o3));
            }
        }
        __syncthreads();   // vmcnt(0) drain: UC data stores complete before tags
        if (tid == 0) {
            ust32(xtag + bt0*16, (u32)(bt0 + 1));
            ust32(xtag + bt1*16, (u32)(bt1 + 1));
            if ((bt0 & 31) > 0) ust32(ttag + (bt0-1)*16, (u32)bt0);
            ust32(ttag + bt0*16, (u32)(bt0 + 1));   // tn[bt0] from targets row bt1
        }
        return;
    }

    // ================= chain role: phase-major passes, no critical-path waits =================
    const int cw = blk - 64;           // 0..63
    const int b  = cw >> 4;
    const int wg = cw & 15;
    const int colbase = wg * 64 + w * 8;   // wave owns cols colbase..+7
    const int row0    = lane * 16;         // lane owns rows row0..+15

    float G[16][8];
    auto ginit = [&]() {
#pragma unroll
        for (int i = 0; i < 16; ++i)
#pragma unroll
            for (int c = 0; c < 8; ++c)
                G[i][c] = (row0 + i == colbase + c) ? 0.01f : 0.0f;
    };

    auto reduce_v = [&](float acc[8]) -> float {
        float t4[8];
#pragma unroll
        for (int c = 0; c < 8; ++c) t4[c] = __shfl_xor(acc[c], 4, 64);
        const bool k2 = (lane & 4) != 0;
        float s4[4];
#pragma unroll
        for (int k = 0; k < 4; ++k) s4[k] = k2 ? (acc[4+k] + t4[4+k]) : (acc[k] + t4[k]);
        float t2[4];
#pragma unroll
        for (int k = 0; k < 4; ++k) t2[k] = __shfl_xor(s4[k], 2, 64);
        const bool k1 = (lane & 2) != 0;
        float s2[2];
#pragma unroll
        for (int k = 0; k < 2; ++k) s2[k] = k1 ? (s4[2+k] + t2[2+k]) : (s4[k] + t2[k]);
        float t1[2];
#pragma unroll
        for (int k = 0; k < 2; ++k) t1[k] = __shfl_xor(s2[k], 1, 64);
        float v = (lane & 1) ? (s2[1] + t1[1]) : (s2[0] + t1[0]);
        v += __shfl_xor(v, 8, 64);
        v += __shfl_xor(v, 16, 64);
        v += __shfl_xor(v, 32, 64);
        return v;   // full sum for col colbase + (lane&7)
    };
    auto publish = [&](u64* dst512, float v) {
        float vx = __shfl_xor(v, 1, 64);
        if (lane < 8 && !(lane & 1))
            ust(dst512 + ((colbase + lane) >> 1), pk2(v, vx));
    };
    auto gupd = [&](const float* x16, int bt) {
        u64 tnp[4];
#pragma unroll
        for (int k = 0; k < 4; ++k) tnp[k] = uld(tn64 + (size_t)bt * 512 + (colbase >> 1) + k);
        float tv[8];
#pragma unroll
        for (int k = 0; k < 4; ++k) { tv[2*k] = 0.5f * flo(tnp[k]); tv[2*k+1] = 0.5f * fhi(tnp[k]); }
#pragma unroll
        for (int c = 0; c < 8; ++c)
#pragma unroll
            for (int i = 0; i < 16; ++i)
                G[i][c] = fmaxf(G[i][c], x16[i] * tv[c]);
    };

    // ---- pass 1: p1_t for all t (waits only on precompute, which runs concurrently) ----
    ginit();
#pragma unroll 1
    for (int t = 0; t < TT; ++t) {
        const int bt = b * TT + t;
        if (tid == 0) {
            int g = 0;
            while (uld32(xtag + bt*16) != (u32)(bt+1) && ++g < (1<<20)) __builtin_amdgcn_s_sleep(1);
            if (t < TT-1) { g = 0;
                while (uld32(ttag + bt*16) != (u32)(bt+1) && ++g < (1<<20)) __builtin_amdgcn_s_sleep(1); }
        }
        __syncthreads();
        u64 xx = uld(xn64 + (size_t)bt * 512 + tid);
        { int i0 = 2*tid, i1 = i0+1; sh[i0+(i0>>4)] = flo(xx); sh[i1+(i1>>4)] = fhi(xx); }
        __syncthreads();
        float in[16];
#pragma unroll
        for (int j = 0; j < 16; ++j) in[j] = sh[lane*17 + j];
        float acc[8] = {0.f,0.f,0.f,0.f,0.f,0.f,0.f,0.f};
#pragma unroll
        for (int i = 0; i < 16; ++i)
#pragma unroll
            for (int c = 0; c < 8; ++c) acc[c] += in[i] * G[i][c];
        float v = reduce_v(acc);
        if (lane < 8) sh[2048 + (w*32 + t)*8 + lane] = v;   // myp1 stash
        publish(p64 + (size_t)(bt*2 + 0) * 512, v);
        if (t < TT-1) gupd(in, bt);   // G_t -> G_{t+1}
        __syncthreads();   // drain publishes
        if (tid == 0) ust32(ptag + (bt*2+0)*16 + wg, (u32)(bt*2 + 1));
    }

    // ---- passes 2,3: p2 / p3+r. G REPLAYED FROM G_0 EACH PASS (R9 bug #1) and
    // updated incrementally every step in BOTH passes (R9 bug #2). Register prefetch
    // of t+1 is safe: tag line observed before data loads are issued.
    for (int pp = 1; pp <= 2; ++pp) {
        ginit();
        u64 pre = 0; bool have = false;
#pragma unroll 1
        for (int t = 0; t < TT; ++t) {
            const int bt = b * TT + t;
            const int srcph = pp - 1;
            const u64* srcp = p64 + (size_t)(bt*2 + srcph) * 512;
            const u32 expt = (u32)(bt*2 + pp);
            if (!have) {
                int g = 0;
                while (true) {
                    u32 tg = uld32(ptag + (bt*2+srcph)*16 + (lane & 15));
                    if (__all(tg == expt)) break;
                    if (++g > (1<<20)) break;
                    __builtin_amdgcn_s_sleep(1);
                }
                pre = uld(srcp + tid);
            }
            __syncthreads();   // protect staging reuse
            { int i0 = 2*tid, i1 = i0+1; sh[i0+(i0>>4)] = flo(pre); sh[i1+(i1>>4)] = fhi(pre); }
            __syncthreads();
            float in[16];
#pragma unroll
            for (int j = 0; j < 16; ++j) in[j] = sh[lane*17 + j];
            // safe prefetch of step t+1's input
            have = false;
            if (t < TT-1) {
                u32 tg = uld32(ptag + ((bt+1)*2+srcph)*16 + (lane & 15));
                if (__all(tg == (u32)((bt+1)*2 + pp))) {
                    pre = uld(p64 + (size_t)((bt+1)*2 + srcph) * 512 + tid);
                    have = true;
                }
            }
            float acc[8] = {0.f,0.f,0.f,0.f,0.f,0.f,0.f,0.f};
#pragma unroll
            for (int i = 0; i < 16; ++i)
#pragma unroll
                for (int c = 0; c < 8; ++c) acc[c] += in[i] * G[i][c];
            float v = reduce_v(acc);
            if (pp == 1) {
                if (lane < 8) sh[4096 + (w*32 + t)*8 + lane] = v;   // myp2 stash
                publish(p64 + (size_t)(bt*2 + 1) * 512, v);
            } else {
                float v1 = sh[2048 + (w*32 + t)*8 + (lane & 7)];
                float v2 = sh[4096 + (w*32 + t)*8 + (lane & 7)];
                float r  = fmaxf(v, fmaxf(v1, v2));
                publish(r64 + (size_t)bt * 512, r);
            }
            // incremental G_t -> G_{t+1} (both passes; xn/tn re-read as UC, validated in pass 1)
            if (t < TT-1) {
                u64 xp[8];
#pragma unroll
                for (int k = 0; k < 8; ++k) xp[k] = uld(xn64 + (size_t)bt*512 + (row0>>1) + k);
                float x16[16];
#pragma unroll
                for (int k = 0; k < 8; ++k) { x16[2*k] = flo(xp[k]); x16[2*k+1] = fhi(xp[k]); }
                gupd(x16, bt);
            }
            __syncthreads();
            if (tid == 0) {
                if (pp == 1) ust32(ptag + (bt*2+1)*16 + wg, (u32)(bt*2 + 2));
                else         ust32(rtag + bt*16 + wg, (u32)(bt + 1));
            }
        }
    }

    // ---- pass 4: y = relu(r @ Dy) for 2 owned timesteps, written straight to out ----
#pragma unroll
    for (int j = 0; j < 2; ++j) {
        const int btj = 2*cw + j;
        int g = 0;
        while (true) {
            u32 tg = uld32(rtag + btj*16 + (lane & 15));
            if (__all(tg == (u32)(btj + 1))) break;
            if (++g > (1<<20)) break;
            __builtin_amdgcn_s_sleep(1);
        }
        u64 rr = uld(r64 + (size_t)btj * 512 + tid);
        sh[j*1024 + 2*tid]     = flo(rr);
        sh[j*1024 + 2*tid + 1] = fhi(rr);
    }
    __syncthreads();
    {
        const int d = tid & 255, h = tid >> 8;
        float ac0 = 0.f, ac1 = 0.f;
#pragma unroll 8
        for (int n = h*512; n < h*512 + 512; ++n) {
            float dv = Dy[(size_t)n * DD + d];
            ac0 += sh[n]        * dv;
            ac1 += sh[1024 + n] * dv;
        }
        sh[2048 + (h*2+0)*256 + d] = ac0;
        sh[2048 + (h*2+1)*256 + d] = ac1;
    }
    __syncthreads();
    if (tid < 256) {
        out[(size_t)(2*cw)   * DD + tid] = fmaxf(0.f, sh[2048 + tid]       + sh[2048 + 512 + tid]);
        out[(size_t)(2*cw+1) * DD + tid] = fmaxf(0.f, sh[2048 + 256 + tid] + sh[2048 + 768 + tid]);
    }
}

extern "C" void kernel_launch(void* const* d_in, const int* in_sizes, int n_in,
                              void* d_out, int out_size, void* d_ws, size_t ws_size,
                              hipStream_t stream) {
    const float* x_seq   = (const float*)d_in[0];
    const float* targets = (const float*)d_in[1];
    const float* E       = (const float*)d_in[2];
    const float* Dy      = (const float*)d_in[3];
    float* out = (float*)d_out;
    float* ws  = (float*)d_ws;

    // Single fused launch: blocks 0..63 precompute, 64..127 chain+output.
    // No memset needed: all shared slots are tag-protected write-once.
    fused_kernel<<<128, 512, 0, stream>>>(x_seq, targets, E, Dy, out, ws);
}